// Round 6
// baseline (292.643 us; speedup 1.0000x reference)
//
#include <hip/hip_runtime.h>

typedef float  f32x4 __attribute__((ext_vector_type(4)));
typedef short  s16x8 __attribute__((ext_vector_type(8)));
typedef short  s16x4 __attribute__((ext_vector_type(4)));

__device__ __forceinline__ float bf2f(short h) {
    union { unsigned u; float f; } v; v.u = ((unsigned)(unsigned short)h) << 16; return v.f;
}
__device__ __forceinline__ short f2bf(float f) {
    union { float f; unsigned u; } v; v.f = f;
    unsigned r = v.u + 0x7FFFu + ((v.u >> 16) & 1u);
    return (short)(r >> 16);
}
__device__ __forceinline__ float sigf(float x) { return 1.f / (1.f + __expf(-x)); }

// async global->LDS, 16B per lane; dest must be wave-uniform base + lane*16
__device__ __forceinline__ void gll16(const void* g, void* l) {
    __builtin_amdgcn_global_load_lds(
        (const __attribute__((address_space(1))) unsigned int*)(uintptr_t)g,
        (__attribute__((address_space(3))) unsigned int*)(uintptr_t)l,
        16, 0, 0);
}

// ---------------- workspace layout (bytes) ----------------
// featT (bf16, 6*2816*256)  : [0, 8650752)            -- dead after k_sampgemm
// Y     (bf16, 16384*256)   : [0, 8388608)            -- overlaps featT (born in k_conv)
// Xp    (bf16, 130*144*256) : [17039360, 26624000)
// w9    (bf16, 9*256*256)   : [26624000, 27803648)
// woT   (bf16, 256*256)     : [27803648, 27934720)
// chan_sums (f32,256)       : [27934720, 27935744)
// mx    (f32,16384)         : [27936768, 28002304)
// av    (f32,16384)         : [28002304, 28067840)

// ---------------- prep: transposes / conversions / zeroing ----------------
__global__ __launch_bounds__(256) void k_prep(
    const float* __restrict__ feat, const float* __restrict__ w_out,
    const float* __restrict__ conv_w, short* __restrict__ featT,
    short* __restrict__ woT, short* __restrict__ w9,
    short* __restrict__ Xp, float* __restrict__ chan_sums)
{
    __shared__ float tile[64][65];
    int b = blockIdx.x, t = threadIdx.x;
    if (b < 2340) {                       // zero Xp
        ((f32x4*)Xp)[b * 256 + t] = (f32x4){0.f, 0.f, 0.f, 0.f};
    } else if (b < 3396) {                // feat (n,c,hw) -> featT (n,hw,c) bf16
        int bb = b - 2340;
        int n = bb / 176, r = bb % 176, ct = r / 44, ht = r % 44;
        int ty = t >> 6, tx = t & 63;
        const float* src = feat + (n * 256 + ct * 64) * 2816 + ht * 64;
        #pragma unroll
        for (int i = 0; i < 16; ++i) {
            int cl = ty * 16 + i;
            tile[cl][tx] = src[cl * 2816 + tx];
        }
        __syncthreads();
        short* dst = featT + (n * 2816 + ht * 64) * 256 + ct * 64;
        #pragma unroll
        for (int i = 0; i < 16; ++i) {
            int row = ty * 16 + i;
            dst[row * 256 + tx] = f2bf(tile[tx][row]);
        }
    } else if (b < 3652) {                // w_out (c,j) -> woT (j,c) bf16
        int idx = (b - 3396) * 256 + t;
        int j = idx >> 8, c = idx & 255;
        woT[j * 256 + c] = f2bf(w_out[c * 256 + j]);
    } else if (b < 3908) {                // conv_w (o,c,kh,kw) -> w9 (k,o,c) bf16
        int oc = (b - 3652) * 256 + t;
        const float* src = conv_w + oc * 9;
        #pragma unroll
        for (int k = 0; k < 9; ++k) w9[k * 65536 + oc] = f2bf(src[k]);
    } else {
        if (t < 256) chan_sums[t] = 0.f;
    }
}

// ---------------- fused sampling + out-projection GEMM ----------------
// Block = 64 queries (4 waves). Phase 1: each wave samples 16 queries, writing
// S rows to XOR-swizzled LDS (granule pg = g ^ (row&7) -> phase-2 ds_read_b128
// conflict-free). Phase 2: GEMM (A from LDS, B=woT from L2) -> padded Xp.
__global__ __launch_bounds__(256) void k_sampgemm(
    const float* __restrict__ bev_q, const float* __restrict__ bev_pos,
    const float* __restrict__ refp, const float* __restrict__ l2i,
    const float* __restrict__ aug, const float* __restrict__ w_pos,
    const float* __restrict__ b_pos, const float* __restrict__ w_attn,
    const float* __restrict__ b_attn, const short* __restrict__ featT,
    const short* __restrict__ woT, const float* __restrict__ b_out,
    short* __restrict__ Xp, float* __restrict__ rp_out)
{
    __shared__ short lS[64 * 256];        // 32 KB, swizzled: (row,granule g) at row*32 + (g^(row&7))

    int tid = threadIdx.x, wave = tid >> 6, lane = tid & 63;
    int p0 = blockIdx.x * 64;

    // ---- phase 1: sampling, 16 queries per wave ----
    for (int i = 0; i < 16; ++i) {
        int r = wave * 16 + i;
        int qi = p0 + r;

        f32x4 qv = *(const f32x4*)(bev_q + qi * 256 + lane * 4);
        {
            f32x4 pv = *(const f32x4*)(bev_pos + qi * 256 + lane * 4);
            qv[0] += pv[0]; qv[1] += pv[1]; qv[2] += pv[2]; qv[3] += pv[3];
        }
        f32x4 wp = *(const f32x4*)(w_pos + lane * 4);
        float op = qv[0]*wp[0] + qv[1]*wp[1] + qv[2]*wp[2] + qv[3]*wp[3];

        float la[6] = {0.f,0.f,0.f,0.f,0.f,0.f};
        const float* wa = w_attn + lane * 24;
        #pragma unroll
        for (int ii = 0; ii < 4; ++ii) {
            #pragma unroll
            for (int n = 0; n < 6; ++n) la[n] += qv[ii] * wa[ii * 6 + n];
        }
        #pragma unroll
        for (int m = 1; m < 64; m <<= 1) {
            op += __shfl_xor(op, m);
            #pragma unroll
            for (int n = 0; n < 6; ++n) la[n] += __shfl_xor(la[n], m);
        }
        float off = op + b_pos[0];
        float attn[6];
        #pragma unroll
        for (int n = 0; n < 6; ++n) attn[n] = sigf(la[n] + b_attn[n]);

        float rx = refp[qi * 3 + 0], ry = refp[qi * 3 + 1], rz = refp[qi * 3 + 2];
        float zc = fminf(fmaxf(rz, 0.f), 1.f);
        float lg = logf(fmaxf(zc, 1e-5f) / fmaxf(1.f - zc, 1e-5f));
        float zn = sigf(lg + off);
        if (lane == 0) {
            rp_out[qi * 3 + 0] = rx;
            rp_out[qi * 3 + 1] = ry;
            rp_out[qi * 3 + 2] = zn;
        }

        float X = rx * 102.4f - 51.2f;
        float Yc = ry * 102.4f - 51.2f;
        float Z = zn * 8.f - 5.f;

        f32x4 acc = {0.f, 0.f, 0.f, 0.f};
        auto corner = [&](int n, int xi, int yi, float w) {
            if (xi >= 0 && xi < 88 && yi >= 0 && yi < 32) {
                s16x4 v = *(const s16x4*)(featT + (((n * 32 + yi) * 88 + xi) << 8) + (lane << 2));
                acc[0] += w * bf2f(v[0]); acc[1] += w * bf2f(v[1]);
                acc[2] += w * bf2f(v[2]); acc[3] += w * bf2f(v[3]);
            }
        };
        for (int n = 0; n < 6; ++n) {
            const float* L = l2i + n * 12;
            float cx = L[0]*X + L[1]*Yc + L[2]*Z  + L[3];
            float cy = L[4]*X + L[5]*Yc + L[6]*Z  + L[7];
            float d  = L[8]*X + L[9]*Yc + L[10]*Z + L[11];
            float dd = fmaxf(d, 1e-5f);
            float ux = cx / dd, uy = cy / dd;
            const float* A = aug + n * 12;
            float ax = A[0]*ux + A[1]*uy + A[2]*d + A[3];
            float ay = A[4]*ux + A[5]*uy + A[6]*d + A[7];
            float gx = (ax * (1.f / 704.f) - 0.5f) * 2.f;
            float gy = (ay * (1.f / 256.f) - 0.5f) * 2.f;
            bool m = (d > 1e-5f) && (gx > -1.f) && (gx < 1.f) && (gy > -1.f) && (gy < 1.f);
            if (m) {
                float ix = (gx + 1.f) * 44.f - 0.5f;
                float iy = (gy + 1.f) * 16.f - 0.5f;
                float x0f = floorf(ix), y0f = floorf(iy);
                float wx1 = ix - x0f, wx0 = 1.f - wx1;
                float wy1 = iy - y0f, wy0 = 1.f - wy1;
                int x0 = (int)x0f, y0 = (int)y0f, x1 = x0 + 1, y1 = y0 + 1;
                float wn = attn[n];
                corner(n, x0, y0, wn * wx0 * wy0);
                corner(n, x1, y0, wn * wx1 * wy0);
                corner(n, x0, y1, wn * wx0 * wy1);
                corner(n, x1, y1, wn * wx1 * wy1);
            }
        }
        s16x4 sv;
        sv[0] = f2bf(acc[0]); sv[1] = f2bf(acc[1]);
        sv[2] = f2bf(acc[2]); sv[3] = f2bf(acc[3]);
        // swizzled LDS store: granule g = lane>>1, half = lane&1
        int g = lane >> 1, hf = lane & 1;
        *(s16x4*)&lS[(r * 32 + (g ^ (r & 7))) * 8 + hf * 4] = sv;
    }
    __syncthreads();

    // ---- phase 2: GEMM out2 = S @ w_out + b + residual -> padded Xp ----
    int l15 = lane & 15, quad = lane >> 4;
    int n0 = wave * 64;
    f32x4 acc[4][4];
    #pragma unroll
    for (int mt = 0; mt < 4; ++mt)
        #pragma unroll
        for (int nt = 0; nt < 4; ++nt) acc[mt][nt] = (f32x4){0.f,0.f,0.f,0.f};

    const short* Bb = woT + (n0 + l15) * 256 + quad * 8;
    #pragma unroll
    for (int kb = 0; kb < 8; ++kb) {
        s16x8 a[4], b[4];
        #pragma unroll
        for (int mt = 0; mt < 4; ++mt) {
            int row = mt * 16 + l15;
            int pg = (quad + kb * 4) ^ (row & 7);
            a[mt] = *(const s16x8*)&lS[(row * 32 + pg) * 8];
        }
        #pragma unroll
        for (int nt = 0; nt < 4; ++nt) b[nt] = *(const s16x8*)(Bb + nt * 4096 + kb * 32);
        #pragma unroll
        for (int mt = 0; mt < 4; ++mt)
            #pragma unroll
            for (int nt = 0; nt < 4; ++nt)
                acc[mt][nt] = __builtin_amdgcn_mfma_f32_16x16x32_bf16(a[mt], b[nt], acc[mt][nt], 0, 0, 0);
    }
    #pragma unroll
    for (int nt = 0; nt < 4; ++nt) {
        int j = n0 + nt * 16 + l15;
        float bo = b_out[j];
        #pragma unroll
        for (int mt = 0; mt < 4; ++mt) {
            #pragma unroll
            for (int r = 0; r < 4; ++r) {
                int p = p0 + mt * 16 + quad * 4 + r;
                float v = acc[mt][nt][r] + bo + bev_q[p * 256 + j];
                int h = p >> 7, w = p & 127;
                Xp[((h + 1) * 144 + (w + 1)) * 256 + j] = f2bf(v);
            }
        }
    }
}

// ---------------- conv3x3 + BN + ReLU + fused channel-sum ----------------
__global__ __launch_bounds__(256) void k_conv(
    const short* __restrict__ Xp, const short* __restrict__ w9,
    const float* __restrict__ conv_b, const float* __restrict__ gamma,
    const float* __restrict__ beta, const float* __restrict__ mean,
    const float* __restrict__ var, short* __restrict__ Y,
    float* __restrict__ chan_sums)
{
    __shared__ short lds[32768];          // buf b at b*16384: A 8192 shorts + B 8192

    int tid = threadIdx.x, wave = tid >> 6, lane = tid & 63;
    int l15 = lane & 15, quad = lane >> 4;
    int sg = lane >> 3, cg = lane & 7;
    int cgx = cg ^ sg;                    // XOR-swizzled source channel-group
    int b = blockIdx.x;
    int och = (b >> 3) & 1;
    int h = (b & 7) * 16 + (b >> 4);      // XCD-swizzle
    int mi = wave & 1, ni = wave >> 1;

    f32x4 acc[4][4];
    #pragma unroll
    for (int mt = 0; mt < 4; ++mt)
        #pragma unroll
        for (int nt = 0; nt < 4; ++nt) acc[mt][nt] = (f32x4){0.f,0.f,0.f,0.f};

    auto stage = [&](int t) {
        int tap = t >> 2, cb = t & 3;
        int kh = tap / 3, kw = tap % 3;
        int c0 = cb << 6;
        const short* wsrc = w9 + (tap << 16) + (och << 15) + c0 + cgx * 8;
        const short* xsrc = Xp + ((h + kh) * 144 + kw) * 256 + c0 + cgx * 8;
        short* la = &lds[(t & 1) << 14];
        short* lb = la + 8192;
        #pragma unroll
        for (int j = 0; j < 4; ++j) {
            int row = j * 32 + wave * 8 + sg;
            int slot = (j * 256 + wave * 64 + lane) * 8;
            gll16(wsrc + row * 256, &la[slot]);
            gll16(xsrc + row * 256, &lb[slot]);
        }
    };

    stage(0);
    for (int t = 0; t < 36; ++t) {
        asm volatile("s_waitcnt vmcnt(0)\n\ts_barrier" ::: "memory");
        if (t < 35) stage(t + 1);
        const short* la = &lds[(t & 1) << 14];
        const short* lb = la + 8192;
        int rsw = l15 & 7;
        #pragma unroll
        for (int s = 0; s < 2; ++s) {
            int cgk = s * 4 + quad;
            int csw = (cgk ^ rsw) * 8;
            s16x8 af[4], bf[4];
            #pragma unroll
            for (int mt = 0; mt < 4; ++mt)
                af[mt] = *(const s16x8*)&la[(mi * 64 + mt * 16 + l15) * 64 + csw];
            #pragma unroll
            for (int nt = 0; nt < 4; ++nt)
                bf[nt] = *(const s16x8*)&lb[(ni * 64 + nt * 16 + l15) * 64 + csw];
            #pragma unroll
            for (int mt = 0; mt < 4; ++mt)
                #pragma unroll
                for (int nt = 0; nt < 4; ++nt)
                    acc[mt][nt] = __builtin_amdgcn_mfma_f32_16x16x32_bf16(af[mt], bf[nt], acc[mt][nt], 0, 0, 0);
        }
    }

    #pragma unroll
    for (int mt = 0; mt < 4; ++mt) {
        #pragma unroll
        for (int r = 0; r < 4; ++r) {
            int o = (och << 7) + mi * 64 + mt * 16 + quad * 4 + r;
            float cb_ = conv_b[o], g = gamma[o], be = beta[o], mu = mean[o];
            float inv = rsqrtf(var[o] + 1e-5f);
            float s = 0.f;
            #pragma unroll
            for (int nt = 0; nt < 4; ++nt) {
                int p = h * 128 + ni * 64 + nt * 16 + l15;
                float v = acc[mt][nt][r] + cb_;
                v = g * (v - mu) * inv + be;
                v = fmaxf(v, 0.f);
                Y[p * 256 + o] = f2bf(v);
                s += v;
            }
            // reduce over the 16 lanes sharing this quad (l15 = 0..15)
            s += __shfl_xor(s, 1);
            s += __shfl_xor(s, 2);
            s += __shfl_xor(s, 4);
            s += __shfl_xor(s, 8);
            if (l15 == 0) atomicAdd(chan_sums + o, s);
        }
    }
}

// ---------------- tail1: SE matvec (per-block) + channel max/mean maps ----------------
__global__ __launch_bounds__(256) void k_tail1(
    const float* __restrict__ chan_sums, const float* __restrict__ se_w,
    const float* __restrict__ se_b, const short* __restrict__ Y,
    float* __restrict__ mx, float* __restrict__ av)
{
    __shared__ float sm[256];
    __shared__ float smx[256];
    int t = threadIdx.x;
    sm[t] = chan_sums[t] * (1.f / 16384.f);
    __syncthreads();
    {
        float a = 0.f;
        for (int c = 0; c < 256; ++c) a += sm[c] * se_w[c * 256 + t];
        smx[t] = sigf(a + se_b[t]);
    }
    __syncthreads();

    int lane = t & 63, wv = t >> 6;
    f32x4 sv = *(const f32x4*)&smx[lane * 4];
    for (int i = 0; i < 16; ++i) {
        int p = blockIdx.x * 64 + i * 4 + wv;
        s16x4 yv = *(const s16x4*)(Y + p * 256 + lane * 4);
        float v0 = bf2f(yv[0]) * sv[0], v1 = bf2f(yv[1]) * sv[1];
        float v2 = bf2f(yv[2]) * sv[2], v3 = bf2f(yv[3]) * sv[3];
        float mval = fmaxf(fmaxf(v0, v1), fmaxf(v2, v3));
        float aval = v0 + v1 + v2 + v3;
        #pragma unroll
        for (int m = 1; m < 64; m <<= 1) {
            mval = fmaxf(mval, __shfl_xor(mval, m));
            aval += __shfl_xor(aval, m);
        }
        if (lane == 0) { mx[p] = mval; av[p] = aval * (1.f / 256.f); }
    }
}

// ---------------- tail2: SE matvec (per-block) + CBAM 7x7 + final scale/store ----------------
__global__ __launch_bounds__(256) void k_tail2(
    const float* __restrict__ chan_sums, const float* __restrict__ se_w,
    const float* __restrict__ se_b, const float* __restrict__ mx,
    const float* __restrict__ av, const float* __restrict__ cw,
    const float* __restrict__ cb, const short* __restrict__ Y,
    float* __restrict__ out0)
{
    __shared__ float sm[256];
    __shared__ float smx[256];
    __shared__ float samap[64];
    int t = threadIdx.x;
    sm[t] = chan_sums[t] * (1.f / 16384.f);
    __syncthreads();
    {
        float a = 0.f;
        for (int c = 0; c < 256; ++c) a += sm[c] * se_w[c * 256 + t];
        smx[t] = sigf(a + se_b[t]);
    }
    __syncthreads();

    int p0 = blockIdx.x * 64;
    if (t < 64) {
        int p = p0 + t;
        int h = p >> 7, w = p & 127;
        float acc = cb[0];
        for (int kh = 0; kh < 7; ++kh) {
            int yy = h + kh - 3;
            if ((unsigned)yy >= 128u) continue;
            for (int kw = 0; kw < 7; ++kw) {
                int xx = w + kw - 3;
                if ((unsigned)xx >= 128u) continue;
                int q = yy * 128 + xx;
                acc += cw[kh * 7 + kw] * mx[q] + cw[49 + kh * 7 + kw] * av[q];
            }
        }
        samap[t] = sigf(acc);
    }
    __syncthreads();

    int lane = t & 63, wv = t >> 6;
    f32x4 sv = *(const f32x4*)&smx[lane * 4];
    for (int i = 0; i < 16; ++i) {
        int r = i * 4 + wv;
        int p = p0 + r;
        float a = samap[r];
        s16x4 yv = *(const s16x4*)(Y + p * 256 + lane * 4);
        f32x4 o;
        o[0] = bf2f(yv[0]) * sv[0] * a;
        o[1] = bf2f(yv[1]) * sv[1] * a;
        o[2] = bf2f(yv[2]) * sv[2] * a;
        o[3] = bf2f(yv[3]) * sv[3] * a;
        *(f32x4*)(out0 + p * 256 + lane * 4) = o;
    }
}

extern "C" void kernel_launch(void* const* d_in, const int* in_sizes, int n_in,
                              void* d_out, int out_size, void* d_ws, size_t ws_size,
                              hipStream_t stream) {
    const float* feat     = (const float*)d_in[0];
    const float* bev_q    = (const float*)d_in[1];
    const float* bev_pos  = (const float*)d_in[2];
    const float* refp     = (const float*)d_in[3];
    const float* l2i      = (const float*)d_in[4];
    const float* aug      = (const float*)d_in[5];
    const float* w_pos    = (const float*)d_in[6];
    const float* b_pos    = (const float*)d_in[7];
    const float* w_attn   = (const float*)d_in[8];
    const float* b_attn   = (const float*)d_in[9];
    const float* w_out    = (const float*)d_in[10];
    const float* b_out    = (const float*)d_in[11];
    const float* conv_w   = (const float*)d_in[12];
    const float* conv_b   = (const float*)d_in[13];
    const float* bn_g     = (const float*)d_in[14];
    const float* bn_b     = (const float*)d_in[15];
    const float* bn_m     = (const float*)d_in[16];
    const float* bn_v     = (const float*)d_in[17];
    const float* se_w     = (const float*)d_in[18];
    const float* se_b     = (const float*)d_in[19];
    const float* cbam_w   = (const float*)d_in[20];
    const float* cbam_b   = (const float*)d_in[21];

    char* ws = (char*)d_ws;
    short* featT     = (short*)(ws + 0);
    short* Ybuf      = (short*)(ws + 0);          // overlaps featT (disjoint lifetime)
    short* Xp        = (short*)(ws + 17039360);
    short* w9        = (short*)(ws + 26624000);
    short* woT       = (short*)(ws + 27803648);
    float* chan_sums = (float*)(ws + 27934720);
    float* mx        = (float*)(ws + 27936768);
    float* av        = (float*)(ws + 28002304);

    float* out0   = (float*)d_out;
    float* rp_out = out0 + 16384 * 256;

    hipLaunchKernelGGL(k_prep, dim3(3909), dim3(256), 0, stream,
                       feat, w_out, conv_w, featT, woT, w9, Xp, chan_sums);
    hipLaunchKernelGGL(k_sampgemm, dim3(256), dim3(256), 0, stream,
                       bev_q, bev_pos, refp, l2i, aug, w_pos, b_pos, w_attn, b_attn,
                       featT, woT, b_out, Xp, rp_out);
    hipLaunchKernelGGL(k_conv, dim3(256), dim3(256), 0, stream,
                       Xp, w9, conv_b, bn_g, bn_b, bn_m, bn_v, Ybuf, chan_sums);
    hipLaunchKernelGGL(k_tail1, dim3(256), dim3(256), 0, stream,
                       chan_sums, se_w, se_b, Ybuf, mx, av);
    hipLaunchKernelGGL(k_tail2, dim3(256), dim3(256), 0, stream,
                       chan_sums, se_w, se_b, mx, av, cbam_w, cbam_b, Ybuf, out0);
}

// Round 7
// 243.470 us; speedup vs baseline: 1.2020x; 1.2020x over previous
//
#include <hip/hip_runtime.h>

typedef float  f32x4 __attribute__((ext_vector_type(4)));
typedef short  s16x8 __attribute__((ext_vector_type(8)));
typedef short  s16x4 __attribute__((ext_vector_type(4)));

__device__ __forceinline__ float bf2f(short h) {
    union { unsigned u; float f; } v; v.u = ((unsigned)(unsigned short)h) << 16; return v.f;
}
__device__ __forceinline__ short f2bf(float f) {
    union { float f; unsigned u; } v; v.f = f;
    unsigned r = v.u + 0x7FFFu + ((v.u >> 16) & 1u);
    return (short)(r >> 16);
}
__device__ __forceinline__ float sigf(float x) { return 1.f / (1.f + __expf(-x)); }

// async global->LDS, 16B per lane; dest must be wave-uniform base + lane*16
__device__ __forceinline__ void gll16(const void* g, void* l) {
    __builtin_amdgcn_global_load_lds(
        (const __attribute__((address_space(1))) unsigned int*)(uintptr_t)g,
        (__attribute__((address_space(3))) unsigned int*)(uintptr_t)l,
        16, 0, 0);
}

// ---------------- workspace layout (bytes) ----------------
// featT (bf16, 6*2816*256)  : [0, 8650752)            -- dead after k_sample
// Y     (bf16, 16384*256)   : [0, 8388608)            -- overlaps featT (born in k_conv)
// S     (bf16, 16384*256)   : [8650752, 17039360)
// Xp    (bf16, 130*144*256) : [17039360, 26624000)
// w9f   (bf16, 9*256*256)   : [26624000, 27803648)    -- fragment-major weight layout
// woT   (bf16, 256*256)     : [27803648, 27934720)
// chan_sums (f32,256)       : [27934720, 27935744)
// sbuf  (f32,256)           : [27935744, 27936768)
// mx    (f32,16384)         : [27936768, 28002304)
// av    (f32,16384)         : [28002304, 28067840)
// amap  (f32,16384)         : [28067840, 28133376)

// ---------------- prep: transposes / conversions / zeroing ----------------
__global__ __launch_bounds__(256) void k_prep(
    const float* __restrict__ feat, const float* __restrict__ w_out,
    const float* __restrict__ conv_w, short* __restrict__ featT,
    short* __restrict__ woT, short* __restrict__ w9f,
    short* __restrict__ Xp, float* __restrict__ chan_sums)
{
    __shared__ float tile[64][65];
    int b = blockIdx.x, t = threadIdx.x;
    if (b < 2340) {                       // zero Xp
        ((f32x4*)Xp)[b * 256 + t] = (f32x4){0.f, 0.f, 0.f, 0.f};
    } else if (b < 3396) {                // feat (n,c,hw) -> featT (n,hw,c) bf16
        int bb = b - 2340;
        int n = bb / 176, r = bb % 176, ct = r / 44, ht = r % 44;
        int ty = t >> 6, tx = t & 63;
        const float* src = feat + (n * 256 + ct * 64) * 2816 + ht * 64;
        #pragma unroll
        for (int i = 0; i < 16; ++i) {
            int cl = ty * 16 + i;
            tile[cl][tx] = src[cl * 2816 + tx];
        }
        __syncthreads();
        short* dst = featT + (n * 2816 + ht * 64) * 256 + ct * 64;
        #pragma unroll
        for (int i = 0; i < 16; ++i) {
            int row = ty * 16 + i;
            dst[row * 256 + tx] = f2bf(tile[tx][row]);
        }
    } else if (b < 3652) {                // w_out (c,j) -> woT (j,c) bf16
        int idx = (b - 3396) * 256 + t;
        int j = idx >> 8, c = idx & 255;
        woT[j * 256 + c] = f2bf(w_out[c * 256 + j]);
    } else if (b < 3908) {                // conv_w (o,c,kh,kw) -> w9f fragment-major:
        // w9f[((k*16 + o>>4)*32 + c>>3)*128 + (o&15)*8 + (c&7)]
        int oc = (b - 3652) * 256 + t;    // o*256 + c
        int o = oc >> 8, c = oc & 255;
        const float* src = conv_w + oc * 9;
        int base = (o >> 4) * 32 * 128 + (c >> 3) * 128 + (o & 15) * 8 + (c & 7);
        #pragma unroll
        for (int k = 0; k < 9; ++k)
            w9f[k * 65536 + base] = f2bf(src[k]);
    } else {
        if (t < 256) chan_sums[t] = 0.f;
    }
}

// ---------------- sampling: one wave per query ----------------
__global__ __launch_bounds__(256) void k_sample(
    const float* __restrict__ bev_q, const float* __restrict__ bev_pos,
    const float* __restrict__ refp, const float* __restrict__ l2i,
    const float* __restrict__ aug, const float* __restrict__ w_pos,
    const float* __restrict__ b_pos, const float* __restrict__ w_attn,
    const float* __restrict__ b_attn, const short* __restrict__ featT,
    short* __restrict__ S, float* __restrict__ rp_out)
{
    int lane = threadIdx.x & 63;
    int qi = blockIdx.x * 4 + (threadIdx.x >> 6);

    f32x4 qv = *(const f32x4*)(bev_q + qi * 256 + lane * 4);
    {
        f32x4 pv = *(const f32x4*)(bev_pos + qi * 256 + lane * 4);
        qv[0] += pv[0]; qv[1] += pv[1]; qv[2] += pv[2]; qv[3] += pv[3];
    }
    f32x4 wp = *(const f32x4*)(w_pos + lane * 4);
    float op = qv[0]*wp[0] + qv[1]*wp[1] + qv[2]*wp[2] + qv[3]*wp[3];

    float la[6] = {0.f,0.f,0.f,0.f,0.f,0.f};
    const float* wa = w_attn + lane * 24;
    #pragma unroll
    for (int i = 0; i < 4; ++i) {
        #pragma unroll
        for (int n = 0; n < 6; ++n) la[n] += qv[i] * wa[i * 6 + n];
    }
    #pragma unroll
    for (int m = 1; m < 64; m <<= 1) {
        op += __shfl_xor(op, m);
        #pragma unroll
        for (int n = 0; n < 6; ++n) la[n] += __shfl_xor(la[n], m);
    }
    float off = op + b_pos[0];
    float attn[6];
    #pragma unroll
    for (int n = 0; n < 6; ++n) attn[n] = sigf(la[n] + b_attn[n]);

    float rx = refp[qi * 3 + 0], ry = refp[qi * 3 + 1], rz = refp[qi * 3 + 2];
    float zc = fminf(fmaxf(rz, 0.f), 1.f);
    float lg = logf(fmaxf(zc, 1e-5f) / fmaxf(1.f - zc, 1e-5f));
    float zn = sigf(lg + off);
    if (lane == 0) {
        rp_out[qi * 3 + 0] = rx;
        rp_out[qi * 3 + 1] = ry;
        rp_out[qi * 3 + 2] = zn;
    }

    float X = rx * 102.4f - 51.2f;
    float Yc = ry * 102.4f - 51.2f;
    float Z = zn * 8.f - 5.f;

    f32x4 acc = {0.f, 0.f, 0.f, 0.f};
    auto corner = [&](int n, int xi, int yi, float w) {
        if (xi >= 0 && xi < 88 && yi >= 0 && yi < 32) {
            s16x4 v = *(const s16x4*)(featT + (((n * 32 + yi) * 88 + xi) << 8) + (lane << 2));
            acc[0] += w * bf2f(v[0]); acc[1] += w * bf2f(v[1]);
            acc[2] += w * bf2f(v[2]); acc[3] += w * bf2f(v[3]);
        }
    };
    for (int n = 0; n < 6; ++n) {
        const float* L = l2i + n * 12;
        float cx = L[0]*X + L[1]*Yc + L[2]*Z  + L[3];
        float cy = L[4]*X + L[5]*Yc + L[6]*Z  + L[7];
        float d  = L[8]*X + L[9]*Yc + L[10]*Z + L[11];
        float dd = fmaxf(d, 1e-5f);
        float ux = cx / dd, uy = cy / dd;
        const float* A = aug + n * 12;
        float ax = A[0]*ux + A[1]*uy + A[2]*d + A[3];
        float ay = A[4]*ux + A[5]*uy + A[6]*d + A[7];
        float gx = (ax * (1.f / 704.f) - 0.5f) * 2.f;
        float gy = (ay * (1.f / 256.f) - 0.5f) * 2.f;
        bool m = (d > 1e-5f) && (gx > -1.f) && (gx < 1.f) && (gy > -1.f) && (gy < 1.f);
        if (m) {
            float ix = (gx + 1.f) * 44.f - 0.5f;
            float iy = (gy + 1.f) * 16.f - 0.5f;
            float x0f = floorf(ix), y0f = floorf(iy);
            float wx1 = ix - x0f, wx0 = 1.f - wx1;
            float wy1 = iy - y0f, wy0 = 1.f - wy1;
            int x0 = (int)x0f, y0 = (int)y0f, x1 = x0 + 1, y1 = y0 + 1;
            float wn = attn[n];
            corner(n, x0, y0, wn * wx0 * wy0);
            corner(n, x1, y0, wn * wx1 * wy0);
            corner(n, x0, y1, wn * wx0 * wy1);
            corner(n, x1, y1, wn * wx1 * wy1);
        }
    }
    s16x4 sv;
    sv[0] = f2bf(acc[0]); sv[1] = f2bf(acc[1]);
    sv[2] = f2bf(acc[2]); sv[3] = f2bf(acc[3]);
    *(s16x4*)(S + qi * 256 + lane * 4) = sv;
}

// ---------------- out-projection GEMM: out2 = S @ w_out + b + residual -> padded Xp ----------------
__global__ __launch_bounds__(256) void k_gemm(
    const short* __restrict__ S, const short* __restrict__ woT,
    const float* __restrict__ b_out, const float* __restrict__ bev_q,
    short* __restrict__ Xp)
{
    int tid = threadIdx.x, wave = tid >> 6, lane = tid & 63;
    int l15 = lane & 15, quad = lane >> 4;
    int p0 = blockIdx.x * 64, n0 = wave * 64;
    f32x4 acc[4][4];
    #pragma unroll
    for (int mt = 0; mt < 4; ++mt)
        #pragma unroll
        for (int nt = 0; nt < 4; ++nt) acc[mt][nt] = (f32x4){0.f,0.f,0.f,0.f};

    const short* Ab = S   + (p0 + l15) * 256 + quad * 8;
    const short* Bb = woT + (n0 + l15) * 256 + quad * 8;
    #pragma unroll
    for (int kb = 0; kb < 8; ++kb) {
        s16x8 a[4], b[4];
        #pragma unroll
        for (int mt = 0; mt < 4; ++mt) a[mt] = *(const s16x8*)(Ab + mt * 4096 + kb * 32);
        #pragma unroll
        for (int nt = 0; nt < 4; ++nt) b[nt] = *(const s16x8*)(Bb + nt * 4096 + kb * 32);
        #pragma unroll
        for (int mt = 0; mt < 4; ++mt)
            #pragma unroll
            for (int nt = 0; nt < 4; ++nt)
                acc[mt][nt] = __builtin_amdgcn_mfma_f32_16x16x32_bf16(a[mt], b[nt], acc[mt][nt], 0, 0, 0);
    }
    #pragma unroll
    for (int nt = 0; nt < 4; ++nt) {
        int j = n0 + nt * 16 + l15;
        float bo = b_out[j];
        #pragma unroll
        for (int mt = 0; mt < 4; ++mt) {
            #pragma unroll
            for (int r = 0; r < 4; ++r) {
                int p = p0 + mt * 16 + quad * 4 + r;
                float v = acc[mt][nt][r] + bo + bev_q[p * 256 + j];
                int h = p >> 7, w = p & 127;
                Xp[((h + 1) * 144 + (w + 1)) * 256 + j] = f2bf(v);
            }
        }
    }
}

// ---------------- conv3x3 + BN + ReLU: A direct from L2 (register-pipelined),
// B-only LDS double buffer (2x8KB), raw s_barrier, XOR swizzle.
// 512 blocks = 2 och-halves x 256 px-tiles(64px), 2 blocks/CU; wave = 64oc x 32px.
__global__ __launch_bounds__(256) void k_conv(
    const short* __restrict__ Xp, const short* __restrict__ w9f,
    const float* __restrict__ conv_b, const float* __restrict__ gamma,
    const float* __restrict__ beta, const float* __restrict__ mean,
    const float* __restrict__ var, short* __restrict__ Y)
{
    __shared__ short lB[8192];            // 2 buffers x 4096 shorts

    int tid = threadIdx.x, wave = tid >> 6, lane = tid & 63;
    int l15 = lane & 15, quad = lane >> 4;
    int sg = lane >> 3, cg = lane & 7;
    int cgx = cg ^ sg;                    // XOR-swizzled source channel-group
    int b = blockIdx.x;
    int xcd = b & 7, bi = b >> 3;         // XCD-swizzle: XCD x owns rows [16x,16x+16)
    int och = bi >> 5, lp = bi & 31;
    int h = xcd * 16 + (lp >> 1);
    int w0 = (lp & 1) * 64;
    int mi = wave >> 1, ni = wave & 1;    // oc 64-half / px 32-half

    f32x4 acc[4][2];
    #pragma unroll
    for (int mt = 0; mt < 4; ++mt)
        #pragma unroll
        for (int nt = 0; nt < 2; ++nt) acc[mt][nt] = (f32x4){0.f,0.f,0.f,0.f};

    s16x8 afr[2][8];                      // ping-pong A fragments [parity][s*4+mt]

    const short* w9base = w9f + ((och * 8 + mi * 4) * 32 + quad) * 128 + l15 * 8;
    auto loadA = [&](int t, int par) {
        int tap = t >> 2, cb = t & 3;
        const short* base = w9base + tap * 65536 + cb * 8 * 128;
        #pragma unroll
        for (int s = 0; s < 2; ++s)
            #pragma unroll
            for (int mt = 0; mt < 4; ++mt)
                afr[par][s * 4 + mt] = *(const s16x8*)(base + (mt * 32 + s * 4) * 128);
    };
    auto stageB = [&](int t) {
        int tap = t >> 2, cb = t & 3;
        int kh = tap / 3, kw = tap % 3;
        const short* xsrc = Xp + ((h + kh) * 144 + (w0 + kw)) * 256 + cb * 64 + cgx * 8;
        short* lb = &lB[(t & 1) << 12];
        #pragma unroll
        for (int j = 0; j < 2; ++j) {
            int px = j * 32 + (tid >> 3);     // px&7 == sg
            gll16(xsrc + px * 256, &lb[(j * 256 + tid) * 8]);
        }
    };

    loadA(0, 0);
    stageB(0);
    #pragma unroll
    for (int t = 0; t < 36; ++t) {
        // drain own A-loads(t) + B-staging(t), raw barrier; then issue t+1
        asm volatile("s_waitcnt vmcnt(0)\n\ts_barrier" ::: "memory");
        if (t < 35) { loadA(t + 1, (t + 1) & 1); stageB(t + 1); }
        const short* lb = &lB[(t & 1) << 12];
        int rsw = l15 & 7;
        #pragma unroll
        for (int s = 0; s < 2; ++s) {
            int cgk = s * 4 + quad;
            int csw = (cgk ^ rsw) * 8;
            s16x8 bf[2];
            #pragma unroll
            for (int nt = 0; nt < 2; ++nt)
                bf[nt] = *(const s16x8*)&lb[(ni * 32 + nt * 16 + l15) * 64 + csw];
            #pragma unroll
            for (int mt = 0; mt < 4; ++mt)
                #pragma unroll
                for (int nt = 0; nt < 2; ++nt)
                    acc[mt][nt] = __builtin_amdgcn_mfma_f32_16x16x32_bf16(
                        afr[t & 1][s * 4 + mt], bf[nt], acc[mt][nt], 0, 0, 0);
        }
    }

    #pragma unroll
    for (int mt = 0; mt < 4; ++mt) {
        #pragma unroll
        for (int r = 0; r < 4; ++r) {
            int o = och * 128 + mi * 64 + mt * 16 + quad * 4 + r;
            float cb_ = conv_b[o], g = gamma[o], be = beta[o], mu = mean[o];
            float inv = rsqrtf(var[o] + 1e-5f);
            #pragma unroll
            for (int nt = 0; nt < 2; ++nt) {
                int p = h * 128 + w0 + ni * 32 + nt * 16 + l15;
                float v = acc[mt][nt][r] + cb_;
                v = g * (v - mu) * inv + be;
                Y[p * 256 + o] = f2bf(fmaxf(v, 0.f));
            }
        }
    }
}

// ---------------- per-channel spatial sums (SE pooling) ----------------
__global__ __launch_bounds__(256) void k_csum(const short* __restrict__ Y, float* __restrict__ chan_sums)
{
    int c = threadIdx.x, p0 = blockIdx.x * 64;
    float s = 0.f;
    for (int i = 0; i < 64; ++i) s += bf2f(Y[(p0 + i) * 256 + c]);
    atomicAdd(chan_sums + c, s);
}

// ---------------- SE matvec: s = sigmoid(mean @ se_w + se_b) ----------------
__global__ __launch_bounds__(256) void k_se(
    const float* __restrict__ chan_sums, const float* __restrict__ se_w,
    const float* __restrict__ se_b, float* __restrict__ sbuf)
{
    __shared__ float m[256];
    int t = threadIdx.x;
    m[t] = chan_sums[t] * (1.f / 16384.f);
    __syncthreads();
    float a = 0.f;
    for (int c = 0; c < 256; ++c) a += m[c] * se_w[c * 256 + t];
    sbuf[t] = sigf(a + se_b[t]);
}

// ---------------- channel max / mean maps (post-SE) ----------------
__global__ __launch_bounds__(256) void k_mxav(
    const short* __restrict__ Y, const float* __restrict__ sbuf,
    float* __restrict__ mx, float* __restrict__ av)
{
    int lane = threadIdx.x & 63;
    int p = blockIdx.x * 4 + (threadIdx.x >> 6);
    f32x4 sv = *(const f32x4*)(sbuf + lane * 4);
    s16x4 yv = *(const s16x4*)(Y + p * 256 + lane * 4);
    float v0 = bf2f(yv[0]) * sv[0], v1 = bf2f(yv[1]) * sv[1];
    float v2 = bf2f(yv[2]) * sv[2], v3 = bf2f(yv[3]) * sv[3];
    float mval = fmaxf(fmaxf(v0, v1), fmaxf(v2, v3));
    float aval = v0 + v1 + v2 + v3;
    #pragma unroll
    for (int m = 1; m < 64; m <<= 1) {
        mval = fmaxf(mval, __shfl_xor(mval, m));
        aval += __shfl_xor(aval, m);
    }
    if (lane == 0) { mx[p] = mval; av[p] = aval * (1.f / 256.f); }
}

// ---------------- CBAM 7x7 spatial conv -> attention map ----------------
__global__ __launch_bounds__(256) void k_cbam(
    const float* __restrict__ mx, const float* __restrict__ av,
    const float* __restrict__ cw, const float* __restrict__ cb,
    float* __restrict__ amap)
{
    int p = blockIdx.x * 256 + threadIdx.x;
    int h = p >> 7, w = p & 127;
    float acc = cb[0];
    for (int kh = 0; kh < 7; ++kh) {
        int yy = h + kh - 3;
        if ((unsigned)yy >= 128u) continue;
        for (int kw = 0; kw < 7; ++kw) {
            int xx = w + kw - 3;
            if ((unsigned)xx >= 128u) continue;
            int q = yy * 128 + xx;
            acc += cw[kh * 7 + kw] * mx[q] + cw[49 + kh * 7 + kw] * av[q];
        }
    }
    amap[p] = sigf(acc);
}

// ---------------- final: out0[p,c] = Y * s[c] * a[p] ----------------
__global__ __launch_bounds__(256) void k_final(
    const short* __restrict__ Y, const float* __restrict__ sbuf,
    const float* __restrict__ amap, float* __restrict__ out0)
{
    int lane = threadIdx.x & 63;
    int p = blockIdx.x * 4 + (threadIdx.x >> 6);
    float a = amap[p];
    f32x4 sv = *(const f32x4*)(sbuf + lane * 4);
    s16x4 yv = *(const s16x4*)(Y + p * 256 + lane * 4);
    f32x4 o;
    o[0] = bf2f(yv[0]) * sv[0] * a;
    o[1] = bf2f(yv[1]) * sv[1] * a;
    o[2] = bf2f(yv[2]) * sv[2] * a;
    o[3] = bf2f(yv[3]) * sv[3] * a;
    *(f32x4*)(out0 + p * 256 + lane * 4) = o;
}

extern "C" void kernel_launch(void* const* d_in, const int* in_sizes, int n_in,
                              void* d_out, int out_size, void* d_ws, size_t ws_size,
                              hipStream_t stream) {
    const float* feat     = (const float*)d_in[0];
    const float* bev_q    = (const float*)d_in[1];
    const float* bev_pos  = (const float*)d_in[2];
    const float* refp     = (const float*)d_in[3];
    const float* l2i      = (const float*)d_in[4];
    const float* aug      = (const float*)d_in[5];
    const float* w_pos    = (const float*)d_in[6];
    const float* b_pos    = (const float*)d_in[7];
    const float* w_attn   = (const float*)d_in[8];
    const float* b_attn   = (const float*)d_in[9];
    const float* w_out    = (const float*)d_in[10];
    const float* b_out    = (const float*)d_in[11];
    const float* conv_w   = (const float*)d_in[12];
    const float* conv_b   = (const float*)d_in[13];
    const float* bn_g     = (const float*)d_in[14];
    const float* bn_b     = (const float*)d_in[15];
    const float* bn_m     = (const float*)d_in[16];
    const float* bn_v     = (const float*)d_in[17];
    const float* se_w     = (const float*)d_in[18];
    const float* se_b     = (const float*)d_in[19];
    const float* cbam_w   = (const float*)d_in[20];
    const float* cbam_b   = (const float*)d_in[21];

    char* ws = (char*)d_ws;
    short* featT     = (short*)(ws + 0);
    short* Ybuf      = (short*)(ws + 0);          // overlaps featT (disjoint lifetime)
    short* Sbuf      = (short*)(ws + 8650752);
    short* Xp        = (short*)(ws + 17039360);
    short* w9f       = (short*)(ws + 26624000);
    short* woT       = (short*)(ws + 27803648);
    float* chan_sums = (float*)(ws + 27934720);
    float* sbuf      = (float*)(ws + 27935744);
    float* mx        = (float*)(ws + 27936768);
    float* av        = (float*)(ws + 28002304);
    float* amap      = (float*)(ws + 28067840);

    float* out0   = (float*)d_out;
    float* rp_out = out0 + 16384 * 256;

    hipLaunchKernelGGL(k_prep, dim3(3909), dim3(256), 0, stream,
                       feat, w_out, conv_w, featT, woT, w9f, Xp, chan_sums);
    hipLaunchKernelGGL(k_sample, dim3(4096), dim3(256), 0, stream,
                       bev_q, bev_pos, refp, l2i, aug, w_pos, b_pos, w_attn, b_attn,
                       featT, Sbuf, rp_out);
    hipLaunchKernelGGL(k_gemm, dim3(256), dim3(256), 0, stream,
                       Sbuf, woT, b_out, bev_q, Xp);
    hipLaunchKernelGGL(k_conv, dim3(512), dim3(256), 0, stream,
                       Xp, w9f, conv_b, bn_g, bn_b, bn_m, bn_v, Ybuf);
    hipLaunchKernelGGL(k_csum, dim3(256), dim3(256), 0, stream, Ybuf, chan_sums);
    hipLaunchKernelGGL(k_se, dim3(1), dim3(256), 0, stream, chan_sums, se_w, se_b, sbuf);
    hipLaunchKernelGGL(k_mxav, dim3(4096), dim3(256), 0, stream, Ybuf, sbuf, mx, av);
    hipLaunchKernelGGL(k_cbam, dim3(64), dim3(256), 0, stream, mx, av, cbam_w, cbam_b, amap);
    hipLaunchKernelGGL(k_final, dim3(4096), dim3(256), 0, stream, Ybuf, sbuf, amap, out0);
}

// Round 8
// 221.069 us; speedup vs baseline: 1.3238x; 1.1013x over previous
//
#include <hip/hip_runtime.h>

typedef float  f32x4 __attribute__((ext_vector_type(4)));
typedef short  s16x8 __attribute__((ext_vector_type(8)));
typedef short  s16x4 __attribute__((ext_vector_type(4)));

__device__ __forceinline__ float bf2f(short h) {
    union { unsigned u; float f; } v; v.u = ((unsigned)(unsigned short)h) << 16; return v.f;
}
__device__ __forceinline__ short f2bf(float f) {
    union { float f; unsigned u; } v; v.f = f;
    unsigned r = v.u + 0x7FFFu + ((v.u >> 16) & 1u);
    return (short)(r >> 16);
}
__device__ __forceinline__ float sigf(float x) { return 1.f / (1.f + __expf(-x)); }

// async global->LDS, 16B per lane; dest must be wave-uniform base + lane*16
__device__ __forceinline__ void gll16(const void* g, void* l) {
    __builtin_amdgcn_global_load_lds(
        (const __attribute__((address_space(1))) unsigned int*)(uintptr_t)g,
        (__attribute__((address_space(3))) unsigned int*)(uintptr_t)l,
        16, 0, 0);
}

// ---------------- workspace layout (bytes) ----------------
// featT (bf16, 6*2816*256)  : [0, 8650752)            -- dead after k_sample
// Y     (bf16, 16384*256)   : [0, 8388608)            -- overlaps featT (born in k_conv)
// S     (bf16, 16384*256)   : [8650752, 17039360)
// Xp    (bf16, 130*144*256) : [17039360, 26624000)
// w9    (bf16, 9*256*256)   : [26624000, 27803648)
// woT   (bf16, 256*256)     : [27803648, 27934720)
// chan_sums (f32,256)       : [27934720, 27935744)
// sbuf  (f32,256)           : [27935744, 27936768)
// mx    (f32,16384)         : [27936768, 28002304)
// av    (f32,16384)         : [28002304, 28067840)
// amap  (f32,16384)         : [28067840, 28133376)

// ---------------- prep: transposes / conversions / zeroing ----------------
__global__ __launch_bounds__(256) void k_prep(
    const float* __restrict__ feat, const float* __restrict__ w_out,
    const float* __restrict__ conv_w, short* __restrict__ featT,
    short* __restrict__ woT, short* __restrict__ w9,
    short* __restrict__ Xp, float* __restrict__ chan_sums)
{
    __shared__ float tile[64][65];
    int b = blockIdx.x, t = threadIdx.x;
    if (b < 2340) {                       // zero Xp
        ((f32x4*)Xp)[b * 256 + t] = (f32x4){0.f, 0.f, 0.f, 0.f};
    } else if (b < 3396) {                // feat (n,c,hw) -> featT (n,hw,c) bf16
        int bb = b - 2340;
        int n = bb / 176, r = bb % 176, ct = r / 44, ht = r % 44;
        int ty = t >> 6, tx = t & 63;
        const float* src = feat + (n * 256 + ct * 64) * 2816 + ht * 64;
        #pragma unroll
        for (int i = 0; i < 16; ++i) {
            int cl = ty * 16 + i;
            tile[cl][tx] = src[cl * 2816 + tx];
        }
        __syncthreads();
        short* dst = featT + (n * 2816 + ht * 64) * 256 + ct * 64;
        #pragma unroll
        for (int i = 0; i < 16; ++i) {
            int row = ty * 16 + i;
            dst[row * 256 + tx] = f2bf(tile[tx][row]);
        }
    } else if (b < 3652) {                // w_out (c,j) -> woT (j,c) bf16
        int idx = (b - 3396) * 256 + t;
        int j = idx >> 8, c = idx & 255;
        woT[j * 256 + c] = f2bf(w_out[c * 256 + j]);
    } else if (b < 3908) {                // conv_w (o,c,kh,kw) -> w9 (k,o,c) bf16
        int oc = (b - 3652) * 256 + t;
        const float* src = conv_w + oc * 9;
        #pragma unroll
        for (int k = 0; k < 9; ++k) w9[k * 65536 + oc] = f2bf(src[k]);
    } else {
        if (t < 256) chan_sums[t] = 0.f;
    }
}

// ---------------- sampling: one wave per query ----------------
__global__ __launch_bounds__(256) void k_sample(
    const float* __restrict__ bev_q, const float* __restrict__ bev_pos,
    const float* __restrict__ refp, const float* __restrict__ l2i,
    const float* __restrict__ aug, const float* __restrict__ w_pos,
    const float* __restrict__ b_pos, const float* __restrict__ w_attn,
    const float* __restrict__ b_attn, const short* __restrict__ featT,
    short* __restrict__ S, float* __restrict__ rp_out)
{
    int lane = threadIdx.x & 63;
    int qi = blockIdx.x * 4 + (threadIdx.x >> 6);

    f32x4 qv = *(const f32x4*)(bev_q + qi * 256 + lane * 4);
    {
        f32x4 pv = *(const f32x4*)(bev_pos + qi * 256 + lane * 4);
        qv[0] += pv[0]; qv[1] += pv[1]; qv[2] += pv[2]; qv[3] += pv[3];
    }
    f32x4 wp = *(const f32x4*)(w_pos + lane * 4);
    float op = qv[0]*wp[0] + qv[1]*wp[1] + qv[2]*wp[2] + qv[3]*wp[3];

    float la[6] = {0.f,0.f,0.f,0.f,0.f,0.f};
    const float* wa = w_attn + lane * 24;
    #pragma unroll
    for (int i = 0; i < 4; ++i) {
        #pragma unroll
        for (int n = 0; n < 6; ++n) la[n] += qv[i] * wa[i * 6 + n];
    }
    #pragma unroll
    for (int m = 1; m < 64; m <<= 1) {
        op += __shfl_xor(op, m);
        #pragma unroll
        for (int n = 0; n < 6; ++n) la[n] += __shfl_xor(la[n], m);
    }
    float off = op + b_pos[0];
    float attn[6];
    #pragma unroll
    for (int n = 0; n < 6; ++n) attn[n] = sigf(la[n] + b_attn[n]);

    float rx = refp[qi * 3 + 0], ry = refp[qi * 3 + 1], rz = refp[qi * 3 + 2];
    float zc = fminf(fmaxf(rz, 0.f), 1.f);
    float lg = logf(fmaxf(zc, 1e-5f) / fmaxf(1.f - zc, 1e-5f));
    float zn = sigf(lg + off);
    if (lane == 0) {
        rp_out[qi * 3 + 0] = rx;
        rp_out[qi * 3 + 1] = ry;
        rp_out[qi * 3 + 2] = zn;
    }

    float X = rx * 102.4f - 51.2f;
    float Yc = ry * 102.4f - 51.2f;
    float Z = zn * 8.f - 5.f;

    f32x4 acc = {0.f, 0.f, 0.f, 0.f};
    auto corner = [&](int n, int xi, int yi, float w) {
        if (xi >= 0 && xi < 88 && yi >= 0 && yi < 32) {
            s16x4 v = *(const s16x4*)(featT + (((n * 32 + yi) * 88 + xi) << 8) + (lane << 2));
            acc[0] += w * bf2f(v[0]); acc[1] += w * bf2f(v[1]);
            acc[2] += w * bf2f(v[2]); acc[3] += w * bf2f(v[3]);
        }
    };
    for (int n = 0; n < 6; ++n) {
        const float* L = l2i + n * 12;
        float cx = L[0]*X + L[1]*Yc + L[2]*Z  + L[3];
        float cy = L[4]*X + L[5]*Yc + L[6]*Z  + L[7];
        float d  = L[8]*X + L[9]*Yc + L[10]*Z + L[11];
        float dd = fmaxf(d, 1e-5f);
        float ux = cx / dd, uy = cy / dd;
        const float* A = aug + n * 12;
        float ax = A[0]*ux + A[1]*uy + A[2]*d + A[3];
        float ay = A[4]*ux + A[5]*uy + A[6]*d + A[7];
        float gx = (ax * (1.f / 704.f) - 0.5f) * 2.f;
        float gy = (ay * (1.f / 256.f) - 0.5f) * 2.f;
        bool m = (d > 1e-5f) && (gx > -1.f) && (gx < 1.f) && (gy > -1.f) && (gy < 1.f);
        if (m) {
            float ix = (gx + 1.f) * 44.f - 0.5f;
            float iy = (gy + 1.f) * 16.f - 0.5f;
            float x0f = floorf(ix), y0f = floorf(iy);
            float wx1 = ix - x0f, wx0 = 1.f - wx1;
            float wy1 = iy - y0f, wy0 = 1.f - wy1;
            int x0 = (int)x0f, y0 = (int)y0f, x1 = x0 + 1, y1 = y0 + 1;
            float wn = attn[n];
            corner(n, x0, y0, wn * wx0 * wy0);
            corner(n, x1, y0, wn * wx1 * wy0);
            corner(n, x0, y1, wn * wx0 * wy1);
            corner(n, x1, y1, wn * wx1 * wy1);
        }
    }
    s16x4 sv;
    sv[0] = f2bf(acc[0]); sv[1] = f2bf(acc[1]);
    sv[2] = f2bf(acc[2]); sv[3] = f2bf(acc[3]);
    *(s16x4*)(S + qi * 256 + lane * 4) = sv;
}

// ---------------- out-projection GEMM: out2 = S @ w_out + b + residual -> padded Xp ----------------
__global__ __launch_bounds__(256) void k_gemm(
    const short* __restrict__ S, const short* __restrict__ woT,
    const float* __restrict__ b_out, const float* __restrict__ bev_q,
    short* __restrict__ Xp)
{
    int tid = threadIdx.x, wave = tid >> 6, lane = tid & 63;
    int l15 = lane & 15, quad = lane >> 4;
    int p0 = blockIdx.x * 64, n0 = wave * 64;
    f32x4 acc[4][4];
    #pragma unroll
    for (int mt = 0; mt < 4; ++mt)
        #pragma unroll
        for (int nt = 0; nt < 4; ++nt) acc[mt][nt] = (f32x4){0.f,0.f,0.f,0.f};

    const short* Ab = S   + (p0 + l15) * 256 + quad * 8;
    const short* Bb = woT + (n0 + l15) * 256 + quad * 8;
    #pragma unroll
    for (int kb = 0; kb < 8; ++kb) {
        s16x8 a[4], b[4];
        #pragma unroll
        for (int mt = 0; mt < 4; ++mt) a[mt] = *(const s16x8*)(Ab + mt * 4096 + kb * 32);
        #pragma unroll
        for (int nt = 0; nt < 4; ++nt) b[nt] = *(const s16x8*)(Bb + nt * 4096 + kb * 32);
        #pragma unroll
        for (int mt = 0; mt < 4; ++mt)
            #pragma unroll
            for (int nt = 0; nt < 4; ++nt)
                acc[mt][nt] = __builtin_amdgcn_mfma_f32_16x16x32_bf16(a[mt], b[nt], acc[mt][nt], 0, 0, 0);
    }
    #pragma unroll
    for (int nt = 0; nt < 4; ++nt) {
        int j = n0 + nt * 16 + l15;
        float bo = b_out[j];
        #pragma unroll
        for (int mt = 0; mt < 4; ++mt) {
            #pragma unroll
            for (int r = 0; r < 4; ++r) {
                int p = p0 + mt * 16 + quad * 4 + r;
                float v = acc[mt][nt][r] + bo + bev_q[p * 256 + j];
                int h = p >> 7, w = p & 127;
                Xp[((h + 1) * 144 + (w + 1)) * 256 + j] = f2bf(v);
            }
        }
    }
}

// ---------------- conv3x3 + BN + ReLU: 128oc x 128px per block, ring-3 LDS pipeline.
// 256 blocks (1/CU). Chunk = tap x 64ch: A 16KB + B 16KB per ring slot (3 x 32KB = 96KB).
// Loads for chunk t are issued at t-2; s_waitcnt vmcnt(8) waits ONLY for chunk t
// (8 gll16/wave/chunk), leaving t+1 in flight across the barrier — no vmcnt(0) drain.
__global__ __launch_bounds__(256) void k_conv(
    const short* __restrict__ Xp, const short* __restrict__ w9,
    const float* __restrict__ conv_b, const float* __restrict__ gamma,
    const float* __restrict__ beta, const float* __restrict__ mean,
    const float* __restrict__ var, short* __restrict__ Y)
{
    __shared__ short lds[49152];          // ring slot r at r*16384: A 8192 shorts + B 8192

    int tid = threadIdx.x, wave = tid >> 6, lane = tid & 63;
    int l15 = lane & 15, quad = lane >> 4;
    int sg = lane >> 3, cg = lane & 7;
    int cgx = cg ^ sg;                    // XOR-swizzled source channel-group (row&7 == sg)
    int b = blockIdx.x;
    int xcd = b & 7, bi = b >> 3;
    int och = bi >> 4;                    // oc half
    int h = xcd * 16 + (bi & 15);         // XCD-swizzle: XCD x owns rows [16x,16x+16)
    int mi = wave & 1, ni = wave >> 1;    // wave quadrant: oc-half / px-half

    f32x4 acc[4][4];
    #pragma unroll
    for (int mt = 0; mt < 4; ++mt)
        #pragma unroll
        for (int nt = 0; nt < 4; ++nt) acc[mt][nt] = (f32x4){0.f,0.f,0.f,0.f};

    auto stage = [&](int t) {
        int tap = t >> 2, cb = t & 3;
        int kh = tap / 3, kw = tap % 3;
        int c0 = cb << 6;
        const short* wsrc = w9 + (tap << 16) + (och << 15) + c0 + cgx * 8;
        const short* xsrc = Xp + ((h + kh) * 144 + kw) * 256 + c0 + cgx * 8;
        short* la = &lds[(t % 3) * 16384];
        short* lb = la + 8192;
        #pragma unroll
        for (int j = 0; j < 4; ++j) {
            int row = j * 32 + wave * 8 + sg;          // 0..127 (oc or px); row&7 == sg
            int slot = (j * 256 + wave * 64 + lane) * 8;
            gll16(wsrc + row * 256, &la[slot]);
            gll16(xsrc + row * 256, &lb[slot]);
        }
    };

    stage(0);
    stage(1);
    #pragma unroll
    for (int t = 0; t < 36; ++t) {
        // wait for chunk t's 8 loads only (t+1's 8 stay in flight), then barrier
        if (t < 35) asm volatile("s_waitcnt vmcnt(8)\n\ts_barrier" ::: "memory");
        else        asm volatile("s_waitcnt vmcnt(0)\n\ts_barrier" ::: "memory");
        if (t < 34) stage(t + 2);
        const short* la = &lds[(t % 3) * 16384];
        const short* lb = la + 8192;
        int rsw = l15 & 7;
        #pragma unroll
        for (int s = 0; s < 2; ++s) {
            int cgk = s * 4 + quad;
            int csw = (cgk ^ rsw) * 8;
            s16x8 af[4], bf[4];
            #pragma unroll
            for (int mt = 0; mt < 4; ++mt)
                af[mt] = *(const s16x8*)&la[(mi * 64 + mt * 16 + l15) * 64 + csw];
            #pragma unroll
            for (int nt = 0; nt < 4; ++nt)
                bf[nt] = *(const s16x8*)&lb[(ni * 64 + nt * 16 + l15) * 64 + csw];
            #pragma unroll
            for (int mt = 0; mt < 4; ++mt)
                #pragma unroll
                for (int nt = 0; nt < 4; ++nt)
                    acc[mt][nt] = __builtin_amdgcn_mfma_f32_16x16x32_bf16(af[mt], bf[nt], acc[mt][nt], 0, 0, 0);
        }
    }

    #pragma unroll
    for (int mt = 0; mt < 4; ++mt) {
        #pragma unroll
        for (int r = 0; r < 4; ++r) {
            int o = (och << 7) + mi * 64 + mt * 16 + quad * 4 + r;
            float cb_ = conv_b[o], g = gamma[o], be = beta[o], mu = mean[o];
            float inv = rsqrtf(var[o] + 1e-5f);
            #pragma unroll
            for (int nt = 0; nt < 4; ++nt) {
                int p = h * 128 + ni * 64 + nt * 16 + l15;
                float v = acc[mt][nt][r] + cb_;
                v = g * (v - mu) * inv + be;
                Y[p * 256 + o] = f2bf(fmaxf(v, 0.f));
            }
        }
    }
}

// ---------------- per-channel spatial sums (SE pooling) ----------------
__global__ __launch_bounds__(256) void k_csum(const short* __restrict__ Y, float* __restrict__ chan_sums)
{
    int c = threadIdx.x, p0 = blockIdx.x * 64;
    float s = 0.f;
    for (int i = 0; i < 64; ++i) s += bf2f(Y[(p0 + i) * 256 + c]);
    atomicAdd(chan_sums + c, s);
}

// ---------------- SE matvec, parallelized over 8 blocks ----------------
// block b computes outputs j in [b*32, b*32+32); thread = (j_local<<3)|cseg,
// partial over c in [cseg*32, cseg*32+32).
__global__ __launch_bounds__(256) void k_se(
    const float* __restrict__ chan_sums, const float* __restrict__ se_w,
    const float* __restrict__ se_b, float* __restrict__ sbuf)
{
    __shared__ float m[256];
    __shared__ float part[256];
    int t = threadIdx.x;
    m[t] = chan_sums[t] * (1.f / 16384.f);
    __syncthreads();
    int j = blockIdx.x * 32 + (t >> 3);
    int cseg = t & 7;
    float a = 0.f;
    #pragma unroll
    for (int i = 0; i < 32; ++i) {
        int c = cseg * 32 + i;
        a += m[c] * se_w[c * 256 + j];
    }
    part[t] = a;
    __syncthreads();
    if (cseg == 0) {
        float s = part[t] + part[t+1] + part[t+2] + part[t+3]
                + part[t+4] + part[t+5] + part[t+6] + part[t+7];
        sbuf[j] = sigf(s + se_b[j]);
    }
}

// ---------------- channel max / mean maps (post-SE) ----------------
__global__ __launch_bounds__(256) void k_mxav(
    const short* __restrict__ Y, const float* __restrict__ sbuf,
    float* __restrict__ mx, float* __restrict__ av)
{
    int lane = threadIdx.x & 63;
    int p = blockIdx.x * 4 + (threadIdx.x >> 6);
    f32x4 sv = *(const f32x4*)(sbuf + lane * 4);
    s16x4 yv = *(const s16x4*)(Y + p * 256 + lane * 4);
    float v0 = bf2f(yv[0]) * sv[0], v1 = bf2f(yv[1]) * sv[1];
    float v2 = bf2f(yv[2]) * sv[2], v3 = bf2f(yv[3]) * sv[3];
    float mval = fmaxf(fmaxf(v0, v1), fmaxf(v2, v3));
    float aval = v0 + v1 + v2 + v3;
    #pragma unroll
    for (int m = 1; m < 64; m <<= 1) {
        mval = fmaxf(mval, __shfl_xor(mval, m));
        aval += __shfl_xor(aval, m);
    }
    if (lane == 0) { mx[p] = mval; av[p] = aval * (1.f / 256.f); }
}

// ---------------- CBAM 7x7 spatial conv -> attention map ----------------
__global__ __launch_bounds__(256) void k_cbam(
    const float* __restrict__ mx, const float* __restrict__ av,
    const float* __restrict__ cw, const float* __restrict__ cb,
    float* __restrict__ amap)
{
    int p = blockIdx.x * 256 + threadIdx.x;
    int h = p >> 7, w = p & 127;
    float acc = cb[0];
    for (int kh = 0; kh < 7; ++kh) {
        int yy = h + kh - 3;
        if ((unsigned)yy >= 128u) continue;
        for (int kw = 0; kw < 7; ++kw) {
            int xx = w + kw - 3;
            if ((unsigned)xx >= 128u) continue;
            int q = yy * 128 + xx;
            acc += cw[kh * 7 + kw] * mx[q] + cw[49 + kh * 7 + kw] * av[q];
        }
    }
    amap[p] = sigf(acc);
}

// ---------------- final: out0[p,c] = Y * s[c] * a[p] ----------------
__global__ __launch_bounds__(256) void k_final(
    const short* __restrict__ Y, const float* __restrict__ sbuf,
    const float* __restrict__ amap, float* __restrict__ out0)
{
    int lane = threadIdx.x & 63;
    int p = blockIdx.x * 4 + (threadIdx.x >> 6);
    float a = amap[p];
    f32x4 sv = *(const f32x4*)(sbuf + lane * 4);
    s16x4 yv = *(const s16x4*)(Y + p * 256 + lane * 4);
    f32x4 o;
    o[0] = bf2f(yv[0]) * sv[0] * a;
    o[1] = bf2f(yv[1]) * sv[1] * a;
    o[2] = bf2f(yv[2]) * sv[2] * a;
    o[3] = bf2f(yv[3]) * sv[3] * a;
    *(f32x4*)(out0 + p * 256 + lane * 4) = o;
}

extern "C" void kernel_launch(void* const* d_in, const int* in_sizes, int n_in,
                              void* d_out, int out_size, void* d_ws, size_t ws_size,
                              hipStream_t stream) {
    const float* feat     = (const float*)d_in[0];
    const float* bev_q    = (const float*)d_in[1];
    const float* bev_pos  = (const float*)d_in[2];
    const float* refp     = (const float*)d_in[3];
    const float* l2i      = (const float*)d_in[4];
    const float* aug      = (const float*)d_in[5];
    const float* w_pos    = (const float*)d_in[6];
    const float* b_pos    = (const float*)d_in[7];
    const float* w_attn   = (const float*)d_in[8];
    const float* b_attn   = (const float*)d_in[9];
    const float* w_out    = (const float*)d_in[10];
    const float* b_out    = (const float*)d_in[11];
    const float* conv_w   = (const float*)d_in[12];
    const float* conv_b   = (const float*)d_in[13];
    const float* bn_g     = (const float*)d_in[14];
    const float* bn_b     = (const float*)d_in[15];
    const float* bn_m     = (const float*)d_in[16];
    const float* bn_v     = (const float*)d_in[17];
    const float* se_w     = (const float*)d_in[18];
    const float* se_b     = (const float*)d_in[19];
    const float* cbam_w   = (const float*)d_in[20];
    const float* cbam_b   = (const float*)d_in[21];

    char* ws = (char*)d_ws;
    short* featT     = (short*)(ws + 0);
    short* Ybuf      = (short*)(ws + 0);          // overlaps featT (disjoint lifetime)
    short* Sbuf      = (short*)(ws + 8650752);
    short* Xp        = (short*)(ws + 17039360);
    short* w9        = (short*)(ws + 26624000);
    short* woT       = (short*)(ws + 27803648);
    float* chan_sums = (float*)(ws + 27934720);
    float* sbuf      = (float*)(ws + 27935744);
    float* mx        = (float*)(ws + 27936768);
    float* av        = (float*)(ws + 28002304);
    float* amap      = (float*)(ws + 28067840);

    float* out0   = (float*)d_out;
    float* rp_out = out0 + 16384 * 256;

    hipLaunchKernelGGL(k_prep, dim3(3909), dim3(256), 0, stream,
                       feat, w_out, conv_w, featT, woT, w9, Xp, chan_sums);
    hipLaunchKernelGGL(k_sample, dim3(4096), dim3(256), 0, stream,
                       bev_q, bev_pos, refp, l2i, aug, w_pos, b_pos, w_attn, b_attn,
                       featT, Sbuf, rp_out);
    hipLaunchKernelGGL(k_gemm, dim3(256), dim3(256), 0, stream,
                       Sbuf, woT, b_out, bev_q, Xp);
    hipLaunchKernelGGL(k_conv, dim3(256), dim3(256), 0, stream,
                       Xp, w9, conv_b, bn_g, bn_b, bn_m, bn_v, Ybuf);
    hipLaunchKernelGGL(k_csum, dim3(256), dim3(256), 0, stream, Ybuf, chan_sums);
    hipLaunchKernelGGL(k_se, dim3(8), dim3(256), 0, stream, chan_sums, se_w, se_b, sbuf);
    hipLaunchKernelGGL(k_mxav, dim3(4096), dim3(256), 0, stream, Ybuf, sbuf, mx, av);
    hipLaunchKernelGGL(k_cbam, dim3(64), dim3(256), 0, stream, mx, av, cbam_w, cbam_b, amap);
    hipLaunchKernelGGL(k_final, dim3(4096), dim3(256), 0, stream, Ybuf, sbuf, amap, out0);
}